// Round 1
// baseline (506.097 us; speedup 1.0000x reference)
//
#include <hip/hip_runtime.h>

#define N_PTS   20000
#define M_ATOMS 10000
#define DAT     64
#define HID     129
#define KNN     16
#define NLAYERS 3

#define TILE_ATOMS 2048
#define NTILES     5          // 5*2048 = 10240 >= 10000
#define M_PAD      10240
#define A_STRIDE   132        // padded row stride for A (16B aligned rows)
#define PTS_PER_WAVE  8
#define PTS_PER_BLOCK 32      // 4 waves * 8

// ---------------- pack y -> float4(x,y,z,|y|^2), INF-padded ----------------
__global__ void pack_y_kernel(const float* __restrict__ y, float4* __restrict__ yp) {
    int i = blockIdx.x * blockDim.x + threadIdx.x;
    if (i >= M_PAD) return;
    if (i < M_ATOMS) {
        float a = y[3*i], b = y[3*i+1], c = y[3*i+2];
        float s = (a*a + b*b) + c*c;          // same order as (y**2).sum(1)
        yp[i] = make_float4(a, b, c, s);
    } else {
        yp[i] = make_float4(0.f, 0.f, 0.f, __builtin_inff());  // pad -> d2=INF
    }
}

// ---------------- brute-force exact kNN (K=16) ----------------
// One wave handles 8 points; top-16 list held distributed in lanes 0..15
// (sorted ascending). Insert = ballot + shfl_up shift: O(1) VALU per insert.
__global__ __launch_bounds__(256) void knn_kernel(
        const float* __restrict__ x, const float4* __restrict__ yp,
        int* __restrict__ oidx, float* __restrict__ odist) {
    __shared__ float4 tile[TILE_ATOMS];     // 32 KiB
    const int tid  = threadIdx.x;
    const int lane = tid & 63;
    const int wid  = tid >> 6;
    const int base_pt = blockIdx.x * PTS_PER_BLOCK + wid * PTS_PER_WAVE;
    const float INF = __builtin_inff();

    // lanes 0..7 hold coords of this wave's 8 points
    float rx0 = 0.f, rx1 = 0.f, rx2 = 0.f, rx3 = 0.f;
    if (lane < PTS_PER_WAVE) {
        int pt = base_pt + lane;
        if (pt < N_PTS) {
            rx0 = x[3*pt]; rx1 = x[3*pt+1]; rx2 = x[3*pt+2];
            rx3 = (rx0*rx0 + rx1*rx1) + rx2*rx2;   // (x**2).sum(1) order
        }
    }

    float Ld[PTS_PER_WAVE];  int Li[PTS_PER_WAVE];  float kth[PTS_PER_WAVE];
#pragma unroll
    for (int p = 0; p < PTS_PER_WAVE; ++p) { Ld[p] = INF; Li[p] = 0; kth[p] = INF; }

    for (int t = 0; t < NTILES; ++t) {
        __syncthreads();
        for (int j = tid; j < TILE_ATOMS; j += 256) tile[j] = yp[t * TILE_ATOMS + j];
        __syncthreads();
        const int abase = t * TILE_ATOMS;
#pragma unroll
        for (int p = 0; p < PTS_PER_WAVE; ++p) {
            const float x0 = __shfl(rx0, p), x1 = __shfl(rx1, p);
            const float x2 = __shfl(rx2, p), xs = __shfl(rx3, p);
            for (int it = 0; it < TILE_ATOMS / 64; ++it) {
                float4 a = tile[it * 64 + lane];
                // selection metric in the SAME algebra as reference:
                // (x2 - 2*dot) + y2
                float dot = (x0 * a.x + x1 * a.y) + x2 * a.z;
                float d2  = (xs - 2.f * dot) + a.w;
                unsigned long long mask = __ballot(d2 < kth[p]);
                while (mask) {                      // uniform loop
                    int src = __builtin_ctzll(mask);  // ascending atom index
                    mask &= mask - 1;
                    float v = __shfl(d2, src);
                    if (v < kth[p]) {               // recheck vs updated kth
                        int mi = abase + it * 64 + src;
                        bool cond = Ld[p] > v;      // strict: stable ties (lower idx first)
                        unsigned long long bal = __ballot(cond);
                        float pd = __shfl_up(Ld[p], 1);
                        int   pi = __shfl_up(Li[p], 1);
                        bool cprev = ((bal << 1) >> lane) & 1ull;
                        Ld[p] = cond ? (cprev ? pd : v)  : Ld[p];
                        Li[p] = cond ? (cprev ? pi : mi) : Li[p];
                        kth[p] = __shfl(Ld[p], 15);
                    }
                }
            }
        }
    }

    // epilogue: recompute exact subtract-form dists for the winners, store
#pragma unroll
    for (int p = 0; p < PTS_PER_WAVE; ++p) {
        int pt = base_pt + p;
        if (pt >= N_PTS) continue;                 // uniform guard
        const float x0 = __shfl(rx0, p), x1 = __shfl(rx1, p), x2 = __shfl(rx2, p);
        int ii = Li[p];                            // valid in lanes 0..15 (always <M_PAD)
        float4 a = yp[ii];
        float dx = x0 - a.x, dy = x1 - a.y, dz = x2 - a.z;
        float dist = (dx*dx + dy*dy) + dz*dz;      // ((x-y)**2).sum(-1) order
        if (lane < KNN) {
            oidx [pt * KNN + lane] = ii;
            odist[pt * KNN + lane] = dist;
        }
    }
}

// ---------------- per-atom precompute: A[l][i][j] = feats[i] @ W1[l][64:128] + b1[l] ----------------
__global__ __launch_bounds__(256) void precompute_A_kernel(
        const float* __restrict__ feats, const float* __restrict__ W1,
        const float* __restrict__ b1, float* __restrict__ A) {
    int wid = threadIdx.x >> 6, lane = threadIdx.x & 63;
    int id = blockIdx.x * 4 + wid;                 // 0 .. 3*M_ATOMS-1
    if (id >= NLAYERS * M_ATOMS) return;
    int l = id / M_ATOMS, i = id - l * M_ATOMS;
    float fi = feats[i * DAT + lane];
    float a0 = 0.f, a1 = 0.f, a2 = 0.f;
    const float* Wl = W1 + (size_t)l * HID * HID;
#pragma unroll 8
    for (int d = 0; d < DAT; ++d) {
        float s = __shfl(fi, d);
        const float* row = Wl + (64 + d) * HID;    // feats rows of W1
        a0 += s * row[lane];
        a1 += s * row[64 + lane];
        a2 += s * row[128];
    }
    float* Ar = A + (size_t)id * A_STRIDE;
    const float* b1l = b1 + l * HID;
    Ar[lane]      = a0 + b1l[lane];
    Ar[64 + lane] = a1 + b1l[64 + lane];
    if (lane == 0) Ar[128] = a2 + b1l[128];
}

// ---------------- fused 3-layer MLP + groupnorm, one wave per point ----------------
__global__ __launch_bounds__(256) void mlp_kernel(
        const float* __restrict__ W1, const float* __restrict__ W2,
        const float* __restrict__ b2, const float* __restrict__ gnw,
        const float* __restrict__ gnb, const float* __restrict__ A,
        const int* __restrict__ oidx, const float* __restrict__ odist,
        float* __restrict__ out) {
    int wid = threadIdx.x >> 6, lane = threadIdx.x & 63;
    int n = blockIdx.x * 4 + wid;
    if (n >= N_PTS) return;

    float pe = 1.0f;                               // point_emb init ones
    int   ik = 0; float dk = 0.f;
    if (lane < KNN) { ik = oidx[n * KNN + lane]; dk = odist[n * KNN + lane]; }

    for (int l = 0; l < NLAYERS; ++l) {
        const float* Wl = W1 + (size_t)l * HID * HID;
        // p = pe @ W1[l][0:64]  (k-independent part); lane covers dims lane, 64+lane, 128
        float p0 = 0.f, p1 = 0.f, p2 = 0.f;
#pragma unroll 8
        for (int d = 0; d < DAT; ++d) {
            float s = __shfl(pe, d);
            const float* row = Wl + d * HID;
            p0 += s * row[lane];
            p1 += s * row[64 + lane];
            p2 += s * row[128];
        }
        const float* wl = Wl + 128 * HID;          // dist row of W1
        float wl0 = wl[lane], wl1 = wl[64 + lane], wl2 = wl[128];

        // hsum = sum_k leaky(p + A[idx_k] + dist_k * wl)
        float hs0 = 0.f, hs1 = 0.f, hs2 = 0.f;
#pragma unroll
        for (int k = 0; k < KNN; ++k) {
            int   ii = __shfl(ik, k);
            float dd = __shfl(dk, k);
            const float* Ar = A + ((size_t)l * M_ATOMS + ii) * A_STRIDE;
            float h0 = p0 + Ar[lane]      + dd * wl0; h0 = h0 >= 0.f ? h0 : 0.2f * h0; hs0 += h0;
            float h1 = p1 + Ar[64 + lane] + dd * wl1; h1 = h1 >= 0.f ? h1 : 0.2f * h1; hs1 += h1;
            float h2 = p2 + Ar[128]       + dd * wl2; h2 = h2 >= 0.f ? h2 : 0.2f * h2; hs2 += h2;
        }

        // msg = hsum @ W2[l] + K*b2[l]   (sum over k hoisted before the matmul)
        const float* W2l = W2 + (size_t)l * HID * DAT;
        float m = 0.f;
#pragma unroll 8
        for (int j = 0; j < DAT; ++j) {
            float a0 = __shfl(hs0, j), a1 = __shfl(hs1, j);
            m += a0 * W2l[j * DAT + lane];
            m += a1 * W2l[(64 + j) * DAT + lane];
        }
        m += hs2 * W2l[128 * DAT + lane];
        m += 16.f * b2[l * DAT + lane];

        // GroupNorm(2 groups of 32 channels) — reduce within aligned 32-lane halves
        float s1 = m;
        s1 += __shfl_xor(s1, 1);  s1 += __shfl_xor(s1, 2);  s1 += __shfl_xor(s1, 4);
        s1 += __shfl_xor(s1, 8);  s1 += __shfl_xor(s1, 16);
        float mu = s1 * (1.f / 32.f);
        float dm = m - mu;
        float s2 = dm * dm;
        s2 += __shfl_xor(s2, 1);  s2 += __shfl_xor(s2, 2);  s2 += __shfl_xor(s2, 4);
        s2 += __shfl_xor(s2, 8);  s2 += __shfl_xor(s2, 16);
        float var = s2 * (1.f / 32.f);
        float g = dm * (1.f / sqrtf(var + 1e-5f)) * gnw[l * DAT + lane] + gnb[l * DAT + lane];
        pe += (g >= 0.f) ? g : 0.2f * g;           // leaky, residual add
    }
    out[n * DAT + lane] = pe;
}

// ---------------- launch ----------------
extern "C" void kernel_launch(void* const* d_in, const int* in_sizes, int n_in,
                              void* d_out, int out_size, void* d_ws, size_t ws_size,
                              hipStream_t stream) {
    const float* x     = (const float*)d_in[0];
    const float* y     = (const float*)d_in[1];
    const float* feats = (const float*)d_in[2];
    const float* W1    = (const float*)d_in[3];
    const float* b1    = (const float*)d_in[4];
    const float* W2    = (const float*)d_in[5];
    const float* b2    = (const float*)d_in[6];
    const float* gnw   = (const float*)d_in[7];
    const float* gnb   = (const float*)d_in[8];
    float* out = (float*)d_out;

    char* ws = (char*)d_ws;
    float4* yp   = (float4*)ws;                         // 10240*16     = 163,840 B
    int*    oidx = (int*)  (ws + 163840);               // 20000*16*4   = 1,280,000 B
    float*  odist= (float*)(ws + 163840 + 1280000);     // 1,280,000 B
    float*  A    = (float*)(ws + 163840 + 2560000);     // 3*10000*132*4 = 15,840,000 B
    // total ~18.6 MB of ws

    pack_y_kernel<<<dim3((M_PAD + 255) / 256), dim3(256), 0, stream>>>(y, yp);
    knn_kernel<<<dim3(N_PTS / PTS_PER_BLOCK), dim3(256), 0, stream>>>(x, yp, oidx, odist);
    precompute_A_kernel<<<dim3((NLAYERS * M_ATOMS) / 4), dim3(256), 0, stream>>>(feats, W1, b1, A);
    mlp_kernel<<<dim3(N_PTS / 4), dim3(256), 0, stream>>>(W1, W2, b2, gnw, gnb, A, oidx, odist, out);
}